// Round 7
// baseline (362.548 us; speedup 1.0000x reference)
//
#include <hip/hip_runtime.h>

#define NN    100000
#define IND   512
#define HID   128
#define OUTD  64
#define NBUCK 782          // ceil(NN/128); bucket = dst >> 7
#define NB    256          // partition chunks

typedef _Float16 half8_t __attribute__((ext_vector_type(8)));
typedef _Float16 half4_t __attribute__((ext_vector_type(4)));
typedef _Float16 half2_t __attribute__((ext_vector_type(2)));
typedef float f32x4 __attribute__((ext_vector_type(4)));

// ---------------- prep: W1t[c][k] = (f16)W1[k][c], W2t[c][k] = (f16)W2[k][c] ----------------
__global__ __launch_bounds__(256) void prep_k(const float* __restrict__ W1,
                                              const float* __restrict__ W2,
                                              _Float16* __restrict__ W1t,
                                              _Float16* __restrict__ W2t) {
    int idx = blockIdx.x * 256 + threadIdx.x;
    if (idx < IND * HID) {             // W1t [128][512]
        int c = idx >> 9, k = idx & 511;
        W1t[idx] = (_Float16)W1[k * HID + c];
    }
    if (idx < HID * OUTD) {            // W2t [64][128]
        int c = idx >> 7, k = idx & 127;
        W2t[idx] = (_Float16)W2[k * OUTD + c];
    }
}

// ---------------- fused GEMM: H2 = relu(F @ W1) @ W2, f16 MFMA, f16 output ----------------
__global__ __launch_bounds__(256) void fused_gemm_k(const float* __restrict__ F,
                                                    const _Float16* __restrict__ W1t,
                                                    const _Float16* __restrict__ W2t,
                                                    _Float16* __restrict__ H2) {
    __shared__ _Float16 At[128 * 64];
    __shared__ _Float16 Bt[128 * 64];
    __shared__ _Float16 W2s[64 * 128];
    __shared__ _Float16 H1s[4][32 * 128];

    const int tid  = threadIdx.x;
    const int wid  = tid >> 6;
    const int lane = tid & 63;
    const int l15  = lane & 15;
    const int l4   = lane >> 4;
    const int brow = blockIdx.x * 128;

#pragma unroll
    for (int i = 0; i < 4; i++) {
        int idx = i * 256 + tid;
        int r = idx >> 4, s = idx & 15;
        int u = (r * 128 + s * 8) ^ ((r & 7) << 3);
        *(uint4*)(&W2s[u]) = *(const uint4*)(W2t + r * 128 + s * 8);
    }

    f32x4 acc[2][8];
#pragma unroll
    for (int mt = 0; mt < 2; mt++)
#pragma unroll
        for (int nt = 0; nt < 8; nt++) acc[mt][nt] = (f32x4)0.f;

    for (int chunk = 0; chunk < 8; chunk++) {
        const int kc = chunk * 64;
#pragma unroll
        for (int i = 0; i < 8; i++) {
            int idx = i * 256 + tid;
            int r = idx >> 4, c4 = idx & 15;
            int gr = brow + r; if (gr >= NN) gr = NN - 1;
            float4 v = *(const float4*)(F + (size_t)gr * IND + kc + c4 * 4);
            half4_t h; h.x = (_Float16)v.x; h.y = (_Float16)v.y; h.z = (_Float16)v.z; h.w = (_Float16)v.w;
            int u = (r * 64 + c4 * 4) ^ ((r & 7) << 3);
            *(half4_t*)(&At[u]) = h;
        }
#pragma unroll
        for (int i = 0; i < 4; i++) {
            int idx = i * 256 + tid;
            int r = idx >> 3, s = idx & 7;
            int u = (r * 64 + s * 8) ^ ((r & 7) << 3);
            *(uint4*)(&Bt[u]) = *(const uint4*)(W1t + (size_t)r * IND + kc + s * 8);
        }
        __syncthreads();
#pragma unroll
        for (int kk = 0; kk < 2; kk++) {
            const int kc2 = kk * 32;
            half8_t af[2];
#pragma unroll
            for (int mt = 0; mt < 2; mt++) {
                int rloc = wid * 32 + mt * 16 + l15;
                int u = (rloc * 64 + kc2 + l4 * 8) ^ ((rloc & 7) << 3);
                af[mt] = *(half8_t*)(&At[u]);
            }
#pragma unroll
            for (int nt = 0; nt < 8; nt++) {
                int cloc = nt * 16 + l15;
                int u = (cloc * 64 + kc2 + l4 * 8) ^ ((cloc & 7) << 3);
                half8_t bf = *(half8_t*)(&Bt[u]);
                acc[0][nt] = __builtin_amdgcn_mfma_f32_16x16x32_f16(af[0], bf, acc[0][nt], 0, 0, 0);
                acc[1][nt] = __builtin_amdgcn_mfma_f32_16x16x32_f16(af[1], bf, acc[1][nt], 0, 0, 0);
            }
        }
        __syncthreads();
    }

#pragma unroll
    for (int mt = 0; mt < 2; mt++)
#pragma unroll
        for (int nt = 0; nt < 8; nt++)
#pragma unroll
            for (int r = 0; r < 4; r++) {
                int rloc = mt * 16 + l4 * 4 + r;
                int col  = nt * 16 + l15;
                float v = acc[mt][nt][r];
                v = v > 0.f ? v : 0.f;
                int u = (rloc * 128 + col) ^ ((rloc & 7) << 3);
                H1s[wid][u] = (_Float16)v;
            }

    f32x4 acc2[2][4];
#pragma unroll
    for (int mt = 0; mt < 2; mt++)
#pragma unroll
        for (int nt = 0; nt < 4; nt++) acc2[mt][nt] = (f32x4)0.f;

#pragma unroll
    for (int kk = 0; kk < 4; kk++) {
        const int kc = kk * 32;
        half8_t a2[2];
#pragma unroll
        for (int mt = 0; mt < 2; mt++) {
            int rloc = mt * 16 + l15;
            int u = (rloc * 128 + kc + l4 * 8) ^ ((rloc & 7) << 3);
            a2[mt] = *(half8_t*)(&H1s[wid][u]);
        }
#pragma unroll
        for (int nt = 0; nt < 4; nt++) {
            int c = nt * 16 + l15;
            int u = (c * 128 + kc + l4 * 8) ^ ((c & 7) << 3);
            half8_t b2 = *(half8_t*)(&W2s[u]);
            acc2[0][nt] = __builtin_amdgcn_mfma_f32_16x16x32_f16(a2[0], b2, acc2[0][nt], 0, 0, 0);
            acc2[1][nt] = __builtin_amdgcn_mfma_f32_16x16x32_f16(a2[1], b2, acc2[1][nt], 0, 0, 0);
        }
    }
#pragma unroll
    for (int mt = 0; mt < 2; mt++)
#pragma unroll
        for (int nt = 0; nt < 4; nt++)
#pragma unroll
            for (int r = 0; r < 4; r++) {
                int grow = brow + wid * 32 + mt * 16 + l4 * 4 + r;
                if (grow < NN) H2[(size_t)grow * OUTD + nt * 16 + l15] = (_Float16)acc2[mt][nt][r];
            }
}

// ---------------- bucket partition (no global atomics; wide launch) ----------------
__global__ __launch_bounds__(1024) void count_k(const int* __restrict__ dst,
                                                int* __restrict__ counts, int nE, int CH) {
    __shared__ int bins[NBUCK];
    const int j = blockIdx.x, tid = threadIdx.x;
    for (int b = tid; b < NBUCK; b += 1024) bins[b] = 0;
    __syncthreads();
    int lo = j * CH, hi = min(lo + CH, nE);
    for (int e = lo + tid; e < hi; e += 1024) atomicAdd(&bins[dst[e] >> 7], 1);
    __syncthreads();
    for (int b = tid; b < NBUCK; b += 1024) counts[b * NB + j] = bins[b];
}

// fused bsum + top-scan + boff: one block, 1024 threads
// in/out: counts[b*NB+j] -> global write offsets; bucketStart[0..NBUCK] written
__global__ __launch_bounds__(1024) void scanall_k(int* __restrict__ counts,
                                                  int* __restrict__ bucketStart) {
    __shared__ int s[1024];
    const int t = threadIdx.x;
    // phase 1: per-bucket totals (thread t owns bucket t; NBUCK < 1024)
    int tot = 0;
    if (t < NBUCK) {
        const int* row = counts + t * NB;
        for (int j = 0; j < NB; j++) tot += row[j];
    }
    s[t] = (t < NBUCK) ? tot : 0;
    __syncthreads();
    // phase 2: inclusive scan
    for (int off = 1; off < 1024; off <<= 1) {
        int x = (t >= off) ? s[t - off] : 0;
        __syncthreads();
        s[t] += x;
        __syncthreads();
    }
    int excl = s[t] - tot;
    if (t < NBUCK) bucketStart[t] = excl;
    if (t == NBUCK - 1) bucketStart[NBUCK] = s[t];
    __syncthreads();
    // phase 3: per-bucket serial prefix over chunks -> absolute offsets
    if (t < NBUCK) {
        int* row = counts + t * NB;
        int run = excl;
        for (int j = 0; j < NB; j++) {
            int c = row[j];
            row[j] = run;
            run += c;
        }
    }
}

// scatter edges into bucket-contiguous edata; cursors in LDS
// payload: x = local_dst(7b)<<17 | src(17b), y = f32 weight bits
__global__ __launch_bounds__(1024) void part_k(const int* __restrict__ src,
                                               const int* __restrict__ dst,
                                               const float* __restrict__ ew,
                                               const int* __restrict__ offsets,
                                               uint2* __restrict__ edata, int nE, int CH) {
    __shared__ int cur[NBUCK];
    const int j = blockIdx.x, tid = threadIdx.x;
    for (int b = tid; b < NBUCK; b += 1024) cur[b] = offsets[b * NB + j];
    __syncthreads();
    int lo = j * CH, hi = min(lo + CH, nE);
    for (int e = lo + tid; e < hi; e += 1024) {
        int d = dst[e];
        int b = d >> 7;
        int pos = atomicAdd(&cur[b], 1);
        edata[pos] = make_uint2(((unsigned)(d & 127) << 17) | (unsigned)src[e],
                                (unsigned)__float_as_int(ew[e]));
    }
}

// per-bucket counting sort -> exact dst-sorted packed edges + rowStart
// epack: src(17b)<<15 | q15 weight
__global__ __launch_bounds__(256) void sort_k(const uint2* __restrict__ edata,
                                              const int* __restrict__ bucketStart,
                                              unsigned* __restrict__ epack,
                                              int* __restrict__ rowStart) {
    __shared__ int bins[128];
    __shared__ int s[128];
    __shared__ int cur[128];
    const int b = blockIdx.x, tid = threadIdx.x;
    if (tid < 128) bins[tid] = 0;
    __syncthreads();
    const int beg = bucketStart[b], end = bucketStart[b + 1];
    for (int e = beg + tid; e < end; e += 256)
        atomicAdd(&bins[edata[e].x >> 17], 1);
    __syncthreads();
    if (tid < 128) s[tid] = bins[tid];
    __syncthreads();
    for (int off = 1; off < 128; off <<= 1) {
        int x = 0;
        if (tid < 128 && tid >= off) x = s[tid - off];
        __syncthreads();
        if (tid < 128) s[tid] += x;
        __syncthreads();
    }
    if (tid < 128) {
        int excl = beg + s[tid] - bins[tid];
        cur[tid] = excl;
        rowStart[b * 128 + tid] = excl;   // rowStart[NN] lands correctly (trailing bins are 0)
    }
    __syncthreads();
    for (int e = beg + tid; e < end; e += 256) {
        uint2 r = edata[e];
        int ld = r.x >> 17;
        int pos = atomicAdd(&cur[ld], 1);
        float w = __int_as_float((int)r.y);
        int q = (int)(w * 32768.f + 0.5f);
        if (q > 32767) q = 32767;
        epack[pos] = ((r.x & 0x1FFFFu) << 15) | (unsigned)q;
    }
}

// ---------------- pull propagate: wave per dst; HALF-wave per edge ----------------
// lanes 0-31 take edge i, lanes 32-63 edge i+1; each lane gathers f16x2 (4 B)
// -> 256 B per gather instruction instead of 128 B.
template <bool LAST>
__global__ __launch_bounds__(256) void pull_k(const _Float16* __restrict__ H,
                                              const unsigned* __restrict__ ep,
                                              const int* __restrict__ rowStart,
                                              _Float16* __restrict__ Zh,
                                              float* __restrict__ Zf) {
    int wave = (int)((blockIdx.x * (long)blockDim.x + threadIdx.x) >> 6);
    int lane = threadIdx.x & 63;
    if (wave >= NN) return;
    const int hw = lane >> 5;      // which edge of the pair
    const int li = lane & 31;      // feature pair: features 2*li, 2*li+1
    int beg = rowStart[wave];
    int end = rowStart[wave + 1];
    float ax = 0.f, ay = 0.f;
    int i = beg;
    for (; i + 8 <= end; i += 8) {
#pragma unroll
        for (int j = 0; j < 4; j++) {
            unsigned u = ep[i + 2 * j + hw];
            half2_t v = *(const half2_t*)(H + (size_t)(u >> 15) * OUTD + li * 2);
            float w = (float)(int)(u & 32767u);
            ax += w * (float)v.x;
            ay += w * (float)v.y;
        }
    }
    for (; i + 2 <= end; i += 2) {
        unsigned u = ep[i + hw];
        half2_t v = *(const half2_t*)(H + (size_t)(u >> 15) * OUTD + li * 2);
        float w = (float)(int)(u & 32767u);
        ax += w * (float)v.x;
        ay += w * (float)v.y;
    }
    if (i < end && hw == 0) {      // odd tail edge: half-wave 0 only
        unsigned u = ep[i];
        half2_t v = *(const half2_t*)(H + (size_t)(u >> 15) * OUTD + li * 2);
        float w = (float)(int)(u & 32767u);
        ax += w * (float)v.x;
        ay += w * (float)v.y;
    }
    // combine the two half-waves (feature f lives at lane li and lane li+32)
    ax += __shfl_xor(ax, 32, 64);
    ay += __shfl_xor(ay, 32, 64);
    ax *= (1.f / 32768.f);
    ay *= (1.f / 32768.f);
    if (hw == 0) {
        if (LAST) {
            *(float2*)(Zf + (size_t)wave * OUTD + li * 2) = make_float2(ax, ay);
        } else {
            half2_t o; o.x = (_Float16)ax; o.y = (_Float16)ay;
            *(half2_t*)(Zh + (size_t)wave * OUTD + li * 2) = o;
        }
    }
}

extern "C" void kernel_launch(void* const* d_in, const int* in_sizes, int n_in,
                              void* d_out, int out_size, void* d_ws, size_t ws_size,
                              hipStream_t stream) {
    const float* F   = (const float*)d_in[0];
    const float* W1  = (const float*)d_in[1];
    const float* W2  = (const float*)d_in[2];
    const float* ew  = (const float*)d_in[3];
    const int*   src = (const int*)d_in[4];
    const int*   dst = (const int*)d_in[5];
    float* out = (float*)d_out;
    const int nE = in_sizes[3];

    // ---- workspace layout ----
    char* p = (char*)d_ws;
    _Float16*  h2        = (_Float16*)p;  p += (size_t)NN * OUTD * sizeof(_Float16);   // 12.8 MB
    _Float16*  z1        = (_Float16*)p;  p += (size_t)NN * OUTD * sizeof(_Float16);   // 12.8 MB
    _Float16*  W1t       = (_Float16*)p;  p += (size_t)HID * IND * sizeof(_Float16);
    _Float16*  W2t       = (_Float16*)p;  p += (size_t)OUTD * HID * sizeof(_Float16);
    int*       counts    = (int*)p;       p += (size_t)NBUCK * NB * sizeof(int);       // 800 KB
    int*       bucketStart=(int*)p;       p += (size_t)(NBUCK + 16) * sizeof(int);
    int*       rowStart  = (int*)p;       p += (size_t)(NN + 160) * sizeof(int);       // 400 KB
    uint2*     edata     = (uint2*)p;     p += (size_t)nE * sizeof(uint2);             // 25.6 MB
    unsigned*  epack     = (unsigned*)p;  p += (size_t)nE * sizeof(unsigned);          // 12.8 MB

    const int CH = (nE + NB - 1) / NB;   // 12500

    // ---- bucket partition + exact sort (no global atomics) ----
    count_k<<<NB, 1024, 0, stream>>>(dst, counts, nE, CH);
    scanall_k<<<1, 1024, 0, stream>>>(counts, bucketStart);
    part_k<<<NB, 1024, 0, stream>>>(src, dst, ew, counts, edata, nE, CH);
    sort_k<<<NBUCK, 256, 0, stream>>>(edata, bucketStart, epack, rowStart);

    // ---- fused NN layers (f16 MFMA) ----
    prep_k<<<(IND * HID + 255) / 256, 256, 0, stream>>>(W1, W2, W1t, W2t);
    fused_gemm_k<<<(NN + 127) / 128, 256, 0, stream>>>(F, W1t, W2t, h2);

    // ---- 2x pull-propagate (f16x2 gathers, f32 accum) ----
    int blocks = (int)(((long)NN * 64 + 255) / 256);
    pull_k<false><<<blocks, 256, 0, stream>>>(h2, epack, rowStart, z1, nullptr);
    pull_k<true><<<blocks, 256, 0, stream>>>(z1, epack, rowStart, nullptr, out);
}

// Round 8
// 340.663 us; speedup vs baseline: 1.0642x; 1.0642x over previous
//
#include <hip/hip_runtime.h>

#define NN    100000
#define IND   512
#define HID   128
#define OUTD  64
#define NBUCK 782          // ceil(NN/128); bucket = dst >> 7
#define NB    256          // partition chunks

typedef _Float16 half8_t __attribute__((ext_vector_type(8)));
typedef _Float16 half4_t __attribute__((ext_vector_type(4)));
typedef float f32x4 __attribute__((ext_vector_type(4)));

// ---------------- prep: W1t[c][k] = (f16)W1[k][c], W2t[c][k] = (f16)W2[k][c] ----------------
__global__ __launch_bounds__(256) void prep_k(const float* __restrict__ W1,
                                              const float* __restrict__ W2,
                                              _Float16* __restrict__ W1t,
                                              _Float16* __restrict__ W2t) {
    int idx = blockIdx.x * 256 + threadIdx.x;
    if (idx < IND * HID) {             // W1t [128][512]
        int c = idx >> 9, k = idx & 511;
        W1t[idx] = (_Float16)W1[k * HID + c];
    }
    if (idx < HID * OUTD) {            // W2t [64][128]
        int c = idx >> 7, k = idx & 127;
        W2t[idx] = (_Float16)W2[k * OUTD + c];
    }
}

// ---------------- fused GEMM: H2 = relu(F @ W1) @ W2, f16 MFMA, f16 output ----------------
// LDS union: H1s strips reuse the At|Bt region (dead after the K-loop's final barrier).
// 48 KB total -> 3 blocks/CU (12 waves/CU) instead of 2.
__global__ __launch_bounds__(256) void fused_gemm_k(const float* __restrict__ F,
                                                    const _Float16* __restrict__ W1t,
                                                    const _Float16* __restrict__ W2t,
                                                    _Float16* __restrict__ H2) {
    __shared__ _Float16 smem[128 * 64 * 2];   // At | Bt, then H1s[4][32*128]
    __shared__ _Float16 W2s[64 * 128];
    _Float16* At = smem;
    _Float16* Bt = smem + 128 * 64;

    const int tid  = threadIdx.x;
    const int wid  = tid >> 6;
    const int lane = tid & 63;
    const int l15  = lane & 15;
    const int l4   = lane >> 4;
    const int brow = blockIdx.x * 128;

#pragma unroll
    for (int i = 0; i < 4; i++) {
        int idx = i * 256 + tid;
        int r = idx >> 4, s = idx & 15;
        int u = (r * 128 + s * 8) ^ ((r & 7) << 3);
        *(uint4*)(&W2s[u]) = *(const uint4*)(W2t + r * 128 + s * 8);
    }

    f32x4 acc[2][8];
#pragma unroll
    for (int mt = 0; mt < 2; mt++)
#pragma unroll
        for (int nt = 0; nt < 8; nt++) acc[mt][nt] = (f32x4)0.f;

    for (int chunk = 0; chunk < 8; chunk++) {
        const int kc = chunk * 64;
#pragma unroll
        for (int i = 0; i < 8; i++) {
            int idx = i * 256 + tid;
            int r = idx >> 4, c4 = idx & 15;
            int gr = brow + r; if (gr >= NN) gr = NN - 1;
            float4 v = *(const float4*)(F + (size_t)gr * IND + kc + c4 * 4);
            half4_t h; h.x = (_Float16)v.x; h.y = (_Float16)v.y; h.z = (_Float16)v.z; h.w = (_Float16)v.w;
            int u = (r * 64 + c4 * 4) ^ ((r & 7) << 3);
            *(half4_t*)(&At[u]) = h;
        }
#pragma unroll
        for (int i = 0; i < 4; i++) {
            int idx = i * 256 + tid;
            int r = idx >> 3, s = idx & 7;
            int u = (r * 64 + s * 8) ^ ((r & 7) << 3);
            *(uint4*)(&Bt[u]) = *(const uint4*)(W1t + (size_t)r * IND + kc + s * 8);
        }
        __syncthreads();
#pragma unroll
        for (int kk = 0; kk < 2; kk++) {
            const int kc2 = kk * 32;
            half8_t af[2];
#pragma unroll
            for (int mt = 0; mt < 2; mt++) {
                int rloc = wid * 32 + mt * 16 + l15;
                int u = (rloc * 64 + kc2 + l4 * 8) ^ ((rloc & 7) << 3);
                af[mt] = *(half8_t*)(&At[u]);
            }
#pragma unroll
            for (int nt = 0; nt < 8; nt++) {
                int cloc = nt * 16 + l15;
                int u = (cloc * 64 + kc2 + l4 * 8) ^ ((cloc & 7) << 3);
                half8_t bf = *(half8_t*)(&Bt[u]);
                acc[0][nt] = __builtin_amdgcn_mfma_f32_16x16x32_f16(af[0], bf, acc[0][nt], 0, 0, 0);
                acc[1][nt] = __builtin_amdgcn_mfma_f32_16x16x32_f16(af[1], bf, acc[1][nt], 0, 0, 0);
            }
        }
        __syncthreads();   // after last iter: all waves' At/Bt reads drained -> safe to reuse
    }

    // relu + f16, wave-private strip [32][128] in the reused region
    _Float16* H1w = smem + wid * (32 * 128);
#pragma unroll
    for (int mt = 0; mt < 2; mt++)
#pragma unroll
        for (int nt = 0; nt < 8; nt++)
#pragma unroll
            for (int r = 0; r < 4; r++) {
                int rloc = mt * 16 + l4 * 4 + r;
                int col  = nt * 16 + l15;
                float v = acc[mt][nt][r];
                v = v > 0.f ? v : 0.f;
                int u = (rloc * 128 + col) ^ ((rloc & 7) << 3);
                H1w[u] = (_Float16)v;
            }
    // wave-private LDS: compiler inserts lgkmcnt waits on dependency; no barrier needed

    f32x4 acc2[2][4];
#pragma unroll
    for (int mt = 0; mt < 2; mt++)
#pragma unroll
        for (int nt = 0; nt < 4; nt++) acc2[mt][nt] = (f32x4)0.f;

#pragma unroll
    for (int kk = 0; kk < 4; kk++) {
        const int kc = kk * 32;
        half8_t a2[2];
#pragma unroll
        for (int mt = 0; mt < 2; mt++) {
            int rloc = mt * 16 + l15;
            int u = (rloc * 128 + kc + l4 * 8) ^ ((rloc & 7) << 3);
            a2[mt] = *(half8_t*)(&H1w[u]);
        }
#pragma unroll
        for (int nt = 0; nt < 4; nt++) {
            int c = nt * 16 + l15;
            int u = (c * 128 + kc + l4 * 8) ^ ((c & 7) << 3);
            half8_t b2 = *(half8_t*)(&W2s[u]);
            acc2[0][nt] = __builtin_amdgcn_mfma_f32_16x16x32_f16(a2[0], b2, acc2[0][nt], 0, 0, 0);
            acc2[1][nt] = __builtin_amdgcn_mfma_f32_16x16x32_f16(a2[1], b2, acc2[1][nt], 0, 0, 0);
        }
    }
#pragma unroll
    for (int mt = 0; mt < 2; mt++)
#pragma unroll
        for (int nt = 0; nt < 4; nt++)
#pragma unroll
            for (int r = 0; r < 4; r++) {
                int grow = brow + wid * 32 + mt * 16 + l4 * 4 + r;
                if (grow < NN) H2[(size_t)grow * OUTD + nt * 16 + l15] = (_Float16)acc2[mt][nt][r];
            }
}

// ---------------- bucket partition (no global atomics; wide launch) ----------------
__global__ __launch_bounds__(1024) void count_k(const int* __restrict__ dst,
                                                int* __restrict__ counts, int nE, int CH) {
    __shared__ int bins[NBUCK];
    const int j = blockIdx.x, tid = threadIdx.x;
    for (int b = tid; b < NBUCK; b += 1024) bins[b] = 0;
    __syncthreads();
    int lo = j * CH, hi = min(lo + CH, nE);
    for (int e = lo + tid; e < hi; e += 1024) atomicAdd(&bins[dst[e] >> 7], 1);
    __syncthreads();
    for (int b = tid; b < NBUCK; b += 1024) counts[b * NB + j] = bins[b];
}

__global__ __launch_bounds__(256) void bsum_k(const int* __restrict__ counts,
                                              int* __restrict__ bsum) {
    __shared__ int s[256];
    const int b = blockIdx.x, t = threadIdx.x;
    s[t] = counts[b * NB + t];
    __syncthreads();
    for (int off = 128; off > 0; off >>= 1) {
        if (t < off) s[t] += s[t + off];
        __syncthreads();
    }
    if (t == 0) bsum[b] = s[0];
}

__global__ __launch_bounds__(1024) void scan_top_k(const int* __restrict__ bsum,
                                                   int* __restrict__ bucketStart, int n) {
    __shared__ int s[1024];
    const int t = threadIdx.x;
    int v = (t < n) ? bsum[t] : 0;
    s[t] = v;
    __syncthreads();
    for (int off = 1; off < 1024; off <<= 1) {
        int x = (t >= off) ? s[t - off] : 0;
        __syncthreads();
        s[t] += x;
        __syncthreads();
    }
    if (t < n) bucketStart[t] = s[t] - v;
    if (t == n - 1) bucketStart[n] = s[t];
}

__global__ __launch_bounds__(256) void boff_k(int* __restrict__ counts,
                                              const int* __restrict__ bucketStart) {
    __shared__ int s[256];
    const int b = blockIdx.x, t = threadIdx.x;
    int v = counts[b * NB + t];
    s[t] = v;
    __syncthreads();
    for (int off = 1; off < 256; off <<= 1) {
        int x = (t >= off) ? s[t - off] : 0;
        __syncthreads();
        s[t] += x;
        __syncthreads();
    }
    counts[b * NB + t] = bucketStart[b] + s[t] - v;
}

// scatter edges into bucket-contiguous edata (single uint payload), cursors in LDS
// payload: ld(7b)<<25 | src(17b)<<8 | q8 weight
__global__ __launch_bounds__(1024) void part_k(const int* __restrict__ src,
                                               const int* __restrict__ dst,
                                               const float* __restrict__ ew,
                                               const int* __restrict__ offsets,
                                               unsigned* __restrict__ edata, int nE, int CH) {
    __shared__ int cur[NBUCK];
    const int j = blockIdx.x, tid = threadIdx.x;
    for (int b = tid; b < NBUCK; b += 1024) cur[b] = offsets[b * NB + j];
    __syncthreads();
    int lo = j * CH, hi = min(lo + CH, nE);
    for (int e = lo + tid; e < hi; e += 1024) {
        int d = dst[e];
        int b = d >> 7;
        int pos = atomicAdd(&cur[b], 1);
        int q = (int)(ew[e] * 255.f + 0.5f);
        if (q > 255) q = 255;
        edata[pos] = ((unsigned)(d & 127) << 25) | ((unsigned)src[e] << 8) | (unsigned)q;
    }
}

// per-bucket counting sort -> exact dst-sorted packed edges + rowStart
// epack: src(17b)<<8 | q8 weight
__global__ __launch_bounds__(256) void sort_k(const unsigned* __restrict__ edata,
                                              const int* __restrict__ bucketStart,
                                              unsigned* __restrict__ epack,
                                              int* __restrict__ rowStart) {
    __shared__ int bins[128];
    __shared__ int s[128];
    __shared__ int cur[128];
    const int b = blockIdx.x, tid = threadIdx.x;
    if (tid < 128) bins[tid] = 0;
    __syncthreads();
    const int beg = bucketStart[b], end = bucketStart[b + 1];
    for (int e = beg + tid; e < end; e += 256)
        atomicAdd(&bins[edata[e] >> 25], 1);
    __syncthreads();
    if (tid < 128) s[tid] = bins[tid];
    __syncthreads();
    for (int off = 1; off < 128; off <<= 1) {
        int x = 0;
        if (tid < 128 && tid >= off) x = s[tid - off];
        __syncthreads();
        if (tid < 128) s[tid] += x;
        __syncthreads();
    }
    if (tid < 128) {
        int excl = beg + s[tid] - bins[tid];
        cur[tid] = excl;
        rowStart[b * 128 + tid] = excl;   // rowStart[NN] lands correctly (trailing bins are 0)
    }
    __syncthreads();
    for (int e = beg + tid; e < end; e += 256) {
        unsigned r = edata[e];
        int ld = r >> 25;
        int pos = atomicAdd(&cur[ld], 1);
        epack[pos] = r & 0x1FFFFFFu;
    }
}

// ---------------- pull propagate: wave per dst, lane = feature, f16 gather ----------------
template <bool LAST>
__global__ __launch_bounds__(256) void pull_k(const _Float16* __restrict__ H,
                                              const unsigned* __restrict__ ep,
                                              const int* __restrict__ rowStart,
                                              _Float16* __restrict__ Zh,
                                              float* __restrict__ Zf) {
    int wave = (int)((blockIdx.x * (long)blockDim.x + threadIdx.x) >> 6);
    int lane = threadIdx.x & 63;
    if (wave >= NN) return;
    int beg = rowStart[wave];
    int end = rowStart[wave + 1];
    float acc = 0.f;
    int i = beg;
    for (; i + 4 <= end; i += 4) {
        unsigned u0 = ep[i], u1 = ep[i + 1], u2 = ep[i + 2], u3 = ep[i + 3];
        float h0 = (float)H[(size_t)(u0 >> 8) * OUTD + lane];
        float h1 = (float)H[(size_t)(u1 >> 8) * OUTD + lane];
        float h2 = (float)H[(size_t)(u2 >> 8) * OUTD + lane];
        float h3 = (float)H[(size_t)(u3 >> 8) * OUTD + lane];
        acc += (float)(int)(u0 & 255u) * h0;
        acc += (float)(int)(u1 & 255u) * h1;
        acc += (float)(int)(u2 & 255u) * h2;
        acc += (float)(int)(u3 & 255u) * h3;
    }
    for (; i < end; i++) {
        unsigned u = ep[i];
        acc += (float)(int)(u & 255u) * (float)H[(size_t)(u >> 8) * OUTD + lane];
    }
    acc *= (1.f / 255.f);
    if (LAST) Zf[(size_t)wave * OUTD + lane] = acc;
    else      Zh[(size_t)wave * OUTD + lane] = (_Float16)acc;
}

extern "C" void kernel_launch(void* const* d_in, const int* in_sizes, int n_in,
                              void* d_out, int out_size, void* d_ws, size_t ws_size,
                              hipStream_t stream) {
    const float* F   = (const float*)d_in[0];
    const float* W1  = (const float*)d_in[1];
    const float* W2  = (const float*)d_in[2];
    const float* ew  = (const float*)d_in[3];
    const int*   src = (const int*)d_in[4];
    const int*   dst = (const int*)d_in[5];
    float* out = (float*)d_out;
    const int nE = in_sizes[3];

    // ---- workspace layout ----
    char* p = (char*)d_ws;
    _Float16*  h2        = (_Float16*)p;  p += (size_t)NN * OUTD * sizeof(_Float16);   // 12.8 MB
    _Float16*  z1        = (_Float16*)p;  p += (size_t)NN * OUTD * sizeof(_Float16);   // 12.8 MB
    _Float16*  W1t       = (_Float16*)p;  p += (size_t)HID * IND * sizeof(_Float16);
    _Float16*  W2t       = (_Float16*)p;  p += (size_t)OUTD * HID * sizeof(_Float16);
    int*       counts    = (int*)p;       p += (size_t)NBUCK * NB * sizeof(int);       // 800 KB
    int*       bsum      = (int*)p;       p += (size_t)NBUCK * sizeof(int);
    int*       bucketStart=(int*)p;       p += (size_t)(NBUCK + 16) * sizeof(int);
    int*       rowStart  = (int*)p;       p += (size_t)(NN + 160) * sizeof(int);       // 400 KB
    unsigned*  edata     = (unsigned*)p;  p += (size_t)nE * sizeof(unsigned);          // 12.8 MB
    unsigned*  epack     = (unsigned*)p;  p += (size_t)nE * sizeof(unsigned);          // 12.8 MB

    const int CH = (nE + NB - 1) / NB;   // 12500

    // ---- bucket partition + exact sort (no global atomics) ----
    count_k<<<NB, 1024, 0, stream>>>(dst, counts, nE, CH);
    bsum_k<<<NBUCK, 256, 0, stream>>>(counts, bsum);
    scan_top_k<<<1, 1024, 0, stream>>>(bsum, bucketStart, NBUCK);
    boff_k<<<NBUCK, 256, 0, stream>>>(counts, bucketStart);
    part_k<<<NB, 1024, 0, stream>>>(src, dst, ew, counts, edata, nE, CH);
    sort_k<<<NBUCK, 256, 0, stream>>>(edata, bucketStart, epack, rowStart);

    // ---- fused NN layers (f16 MFMA) ----
    prep_k<<<(IND * HID + 255) / 256, 256, 0, stream>>>(W1, W2, W1t, W2t);
    fused_gemm_k<<<(NN + 127) / 128, 256, 0, stream>>>(F, W1t, W2t, h2);

    // ---- 2x pull-propagate (f16 gathers, f32 accum) ----
    int blocks = (int)(((long)NN * 64 + 255) / 256);
    pull_k<false><<<blocks, 256, 0, stream>>>(h2, epack, rowStart, z1, nullptr);
    pull_k<true><<<blocks, 256, 0, stream>>>(z1, epack, rowStart, nullptr, out);
}

// Round 9
// 287.530 us; speedup vs baseline: 1.2609x; 1.1848x over previous
//
#include <hip/hip_runtime.h>

#define NN    100000
#define IND   512
#define HID   128
#define OUTD  64
#define NBUCK 782          // ceil(NN/128); bucket = dst >> 7
#define NB    256          // partition chunks
#define NGEMM 782          // (NN+127)/128
#define NPREP 64           // prep blocks appended to count launch

typedef _Float16 half8_t __attribute__((ext_vector_type(8)));
typedef _Float16 half4_t __attribute__((ext_vector_type(4)));
typedef float f32x4 __attribute__((ext_vector_type(4)));

// ---------------- count (blocks 0..NB-1) + prep (blocks NB..NB+NPREP-1) ----------------
__global__ __launch_bounds__(1024) void countprep_k(const int* __restrict__ dst,
                                                    int* __restrict__ counts, int nE, int CH,
                                                    const float* __restrict__ W1,
                                                    const float* __restrict__ W2,
                                                    _Float16* __restrict__ W1t,
                                                    _Float16* __restrict__ W2t) {
    __shared__ int bins[NBUCK];
    const int bid = blockIdx.x, tid = threadIdx.x;
    if (bid >= NB) {   // prep: W1t[c][k] = (f16)W1[k][c], W2t[c][k] = (f16)W2[k][c]
        int idx = (bid - NB) * 1024 + tid;
        if (idx < IND * HID) { int c = idx >> 9, k = idx & 511; W1t[idx] = (_Float16)W1[k * HID + c]; }
        if (idx < HID * OUTD) { int c = idx >> 7, k = idx & 127; W2t[idx] = (_Float16)W2[k * OUTD + c]; }
        return;
    }
    for (int b = tid; b < NBUCK; b += 1024) bins[b] = 0;
    __syncthreads();
    int lo = bid * CH, hi = min(lo + CH, nE);
    for (int e = lo + tid; e < hi; e += 1024) atomicAdd(&bins[dst[e] >> 7], 1);
    __syncthreads();
    for (int b = tid; b < NBUCK; b += 1024) counts[b * NB + bid] = bins[b];
}

__global__ __launch_bounds__(256) void bsum_k(const int* __restrict__ counts,
                                              int* __restrict__ bsum) {
    __shared__ int s[256];
    const int b = blockIdx.x, t = threadIdx.x;
    s[t] = counts[b * NB + t];
    __syncthreads();
    for (int off = 128; off > 0; off >>= 1) {
        if (t < off) s[t] += s[t + off];
        __syncthreads();
    }
    if (t == 0) bsum[b] = s[0];
}

__global__ __launch_bounds__(1024) void scan_top_k(const int* __restrict__ bsum,
                                                   int* __restrict__ bucketStart, int n) {
    __shared__ int s[1024];
    const int t = threadIdx.x;
    int v = (t < n) ? bsum[t] : 0;
    s[t] = v;
    __syncthreads();
    for (int off = 1; off < 1024; off <<= 1) {
        int x = (t >= off) ? s[t - off] : 0;
        __syncthreads();
        s[t] += x;
        __syncthreads();
    }
    if (t < n) bucketStart[t] = s[t] - v;
    if (t == n - 1) bucketStart[n] = s[t];
}

__global__ __launch_bounds__(256) void boff_k(int* __restrict__ counts,
                                              const int* __restrict__ bucketStart) {
    __shared__ int s[256];
    const int b = blockIdx.x, t = threadIdx.x;
    int v = counts[b * NB + t];
    s[t] = v;
    __syncthreads();
    for (int off = 1; off < 256; off <<= 1) {
        int x = (t >= off) ? s[t - off] : 0;
        __syncthreads();
        s[t] += x;
        __syncthreads();
    }
    counts[b * NB + t] = bucketStart[b] + s[t] - v;
}

// scatter edges into bucket-contiguous edata (single uint payload), cursors in LDS
// payload: ld(7b)<<25 | src(17b)<<8 | q8 weight
__global__ __launch_bounds__(1024) void part_k(const int* __restrict__ src,
                                               const int* __restrict__ dst,
                                               const float* __restrict__ ew,
                                               const int* __restrict__ offsets,
                                               unsigned* __restrict__ edata, int nE, int CH) {
    __shared__ int cur[NBUCK];
    const int j = blockIdx.x, tid = threadIdx.x;
    for (int b = tid; b < NBUCK; b += 1024) cur[b] = offsets[b * NB + j];
    __syncthreads();
    int lo = j * CH, hi = min(lo + CH, nE);
    for (int e = lo + tid; e < hi; e += 1024) {
        int d = dst[e];
        int b = d >> 7;
        int pos = atomicAdd(&cur[b], 1);
        int q = (int)(ew[e] * 255.f + 0.5f);
        if (q > 255) q = 255;
        edata[pos] = ((unsigned)(d & 127) << 25) | ((unsigned)src[e] << 8) | (unsigned)q;
    }
}

// ---------------- fat kernel: sort (blocks 0..NBUCK-1) || fused gemm (NBUCK..NBUCK+NGEMM-1) ----
// Sort blocks dispatch first (shorter); gemm blocks backfill -> sort hides under gemm stream.
__global__ __launch_bounds__(256) void gemmsort_k(const float* __restrict__ F,
                                                  const _Float16* __restrict__ W1t,
                                                  const _Float16* __restrict__ W2t,
                                                  _Float16* __restrict__ H2,
                                                  const unsigned* __restrict__ edata,
                                                  const int* __restrict__ bucketStart,
                                                  unsigned* __restrict__ epack,
                                                  int* __restrict__ rowStart) {
    __shared__ _Float16 smem[128 * 64 * 2];   // gemm: At|Bt then H1s; sort: bins|s|cur (ints)
    __shared__ _Float16 W2s[64 * 128];
    const int tid = threadIdx.x;

    if (blockIdx.x < NBUCK) {
        // ---------- per-bucket counting sort ----------
        int* bins = (int*)smem;
        int* s    = bins + 128;
        int* cur  = bins + 256;
        const int b = blockIdx.x;
        if (tid < 128) bins[tid] = 0;
        __syncthreads();
        const int beg = bucketStart[b], end = bucketStart[b + 1];
        for (int e = beg + tid; e < end; e += 256)
            atomicAdd(&bins[edata[e] >> 25], 1);
        __syncthreads();
        if (tid < 128) s[tid] = bins[tid];
        __syncthreads();
        for (int off = 1; off < 128; off <<= 1) {
            int x = 0;
            if (tid < 128 && tid >= off) x = s[tid - off];
            __syncthreads();
            if (tid < 128) s[tid] += x;
            __syncthreads();
        }
        if (tid < 128) {
            int excl = beg + s[tid] - bins[tid];
            cur[tid] = excl;
            rowStart[b * 128 + tid] = excl;
        }
        __syncthreads();
        for (int e = beg + tid; e < end; e += 256) {
            unsigned r = edata[e];
            int ld = r >> 25;
            int pos = atomicAdd(&cur[ld], 1);
            epack[pos] = r & 0x1FFFFFFu;
        }
        return;
    }

    // ---------- fused GEMM: H2 = relu(F @ W1) @ W2 ----------
    _Float16* At = smem;
    _Float16* Bt = smem + 128 * 64;
    const int wid  = tid >> 6;
    const int lane = tid & 63;
    const int l15  = lane & 15;
    const int l4   = lane >> 4;
    const int brow = (blockIdx.x - NBUCK) * 128;

#pragma unroll
    for (int i = 0; i < 4; i++) {
        int idx = i * 256 + tid;
        int r = idx >> 4, sl = idx & 15;
        int u = (r * 128 + sl * 8) ^ ((r & 7) << 3);
        *(uint4*)(&W2s[u]) = *(const uint4*)(W2t + r * 128 + sl * 8);
    }

    f32x4 acc[2][8];
#pragma unroll
    for (int mt = 0; mt < 2; mt++)
#pragma unroll
        for (int nt = 0; nt < 8; nt++) acc[mt][nt] = (f32x4)0.f;

    for (int chunk = 0; chunk < 8; chunk++) {
        const int kc = chunk * 64;
#pragma unroll
        for (int i = 0; i < 8; i++) {
            int idx = i * 256 + tid;
            int r = idx >> 4, c4 = idx & 15;
            int gr = brow + r; if (gr >= NN) gr = NN - 1;
            float4 v = *(const float4*)(F + (size_t)gr * IND + kc + c4 * 4);
            half4_t h; h.x = (_Float16)v.x; h.y = (_Float16)v.y; h.z = (_Float16)v.z; h.w = (_Float16)v.w;
            int u = (r * 64 + c4 * 4) ^ ((r & 7) << 3);
            *(half4_t*)(&At[u]) = h;
        }
#pragma unroll
        for (int i = 0; i < 4; i++) {
            int idx = i * 256 + tid;
            int r = idx >> 3, sl = idx & 7;
            int u = (r * 64 + sl * 8) ^ ((r & 7) << 3);
            *(uint4*)(&Bt[u]) = *(const uint4*)(W1t + (size_t)r * IND + kc + sl * 8);
        }
        __syncthreads();
#pragma unroll
        for (int kk = 0; kk < 2; kk++) {
            const int kc2 = kk * 32;
            half8_t af[2];
#pragma unroll
            for (int mt = 0; mt < 2; mt++) {
                int rloc = wid * 32 + mt * 16 + l15;
                int u = (rloc * 64 + kc2 + l4 * 8) ^ ((rloc & 7) << 3);
                af[mt] = *(half8_t*)(&At[u]);
            }
#pragma unroll
            for (int nt = 0; nt < 8; nt++) {
                int cloc = nt * 16 + l15;
                int u = (cloc * 64 + kc2 + l4 * 8) ^ ((cloc & 7) << 3);
                half8_t bf = *(half8_t*)(&Bt[u]);
                acc[0][nt] = __builtin_amdgcn_mfma_f32_16x16x32_f16(af[0], bf, acc[0][nt], 0, 0, 0);
                acc[1][nt] = __builtin_amdgcn_mfma_f32_16x16x32_f16(af[1], bf, acc[1][nt], 0, 0, 0);
            }
        }
        __syncthreads();   // after last iter: At/Bt reads drained -> safe to reuse for H1s
    }

    _Float16* H1w = smem + wid * (32 * 128);
#pragma unroll
    for (int mt = 0; mt < 2; mt++)
#pragma unroll
        for (int nt = 0; nt < 8; nt++)
#pragma unroll
            for (int r = 0; r < 4; r++) {
                int rloc = mt * 16 + l4 * 4 + r;
                int col  = nt * 16 + l15;
                float v = acc[mt][nt][r];
                v = v > 0.f ? v : 0.f;
                int u = (rloc * 128 + col) ^ ((rloc & 7) << 3);
                H1w[u] = (_Float16)v;
            }
    // wave-private strip: lgkmcnt dependency ordering, no barrier needed

    f32x4 acc2[2][4];
#pragma unroll
    for (int mt = 0; mt < 2; mt++)
#pragma unroll
        for (int nt = 0; nt < 4; nt++) acc2[mt][nt] = (f32x4)0.f;

#pragma unroll
    for (int kk = 0; kk < 4; kk++) {
        const int kc = kk * 32;
        half8_t a2[2];
#pragma unroll
        for (int mt = 0; mt < 2; mt++) {
            int rloc = mt * 16 + l15;
            int u = (rloc * 128 + kc + l4 * 8) ^ ((rloc & 7) << 3);
            a2[mt] = *(half8_t*)(&H1w[u]);
        }
#pragma unroll
        for (int nt = 0; nt < 4; nt++) {
            int c = nt * 16 + l15;
            int u = (c * 128 + kc + l4 * 8) ^ ((c & 7) << 3);
            half8_t b2 = *(half8_t*)(&W2s[u]);
            acc2[0][nt] = __builtin_amdgcn_mfma_f32_16x16x32_f16(a2[0], b2, acc2[0][nt], 0, 0, 0);
            acc2[1][nt] = __builtin_amdgcn_mfma_f32_16x16x32_f16(a2[1], b2, acc2[1][nt], 0, 0, 0);
        }
    }
#pragma unroll
    for (int mt = 0; mt < 2; mt++)
#pragma unroll
        for (int nt = 0; nt < 4; nt++)
#pragma unroll
            for (int r = 0; r < 4; r++) {
                int grow = brow + wid * 32 + mt * 16 + l4 * 4 + r;
                if (grow < NN) H2[(size_t)grow * OUTD + nt * 16 + l15] = (_Float16)acc2[mt][nt][r];
            }
}

// ---------------- pull propagate: wave per dst, lane = feature, unroll 8 ----------------
template <bool LAST>
__global__ __launch_bounds__(256) void pull_k(const _Float16* __restrict__ H,
                                              const unsigned* __restrict__ ep,
                                              const int* __restrict__ rowStart,
                                              _Float16* __restrict__ Zh,
                                              float* __restrict__ Zf) {
    int wave = (int)((blockIdx.x * (long)blockDim.x + threadIdx.x) >> 6);
    int lane = threadIdx.x & 63;
    if (wave >= NN) return;
    int beg = rowStart[wave];
    int end = rowStart[wave + 1];
    float acc = 0.f;
    int i = beg;
    for (; i + 8 <= end; i += 8) {
        unsigned u0 = ep[i],     u1 = ep[i + 1], u2 = ep[i + 2], u3 = ep[i + 3];
        unsigned u4 = ep[i + 4], u5 = ep[i + 5], u6 = ep[i + 6], u7 = ep[i + 7];
        float h0 = (float)H[(size_t)(u0 >> 8) * OUTD + lane];
        float h1 = (float)H[(size_t)(u1 >> 8) * OUTD + lane];
        float h2 = (float)H[(size_t)(u2 >> 8) * OUTD + lane];
        float h3 = (float)H[(size_t)(u3 >> 8) * OUTD + lane];
        float h4 = (float)H[(size_t)(u4 >> 8) * OUTD + lane];
        float h5 = (float)H[(size_t)(u5 >> 8) * OUTD + lane];
        float h6 = (float)H[(size_t)(u6 >> 8) * OUTD + lane];
        float h7 = (float)H[(size_t)(u7 >> 8) * OUTD + lane];
        acc += (float)(int)(u0 & 255u) * h0;
        acc += (float)(int)(u1 & 255u) * h1;
        acc += (float)(int)(u2 & 255u) * h2;
        acc += (float)(int)(u3 & 255u) * h3;
        acc += (float)(int)(u4 & 255u) * h4;
        acc += (float)(int)(u5 & 255u) * h5;
        acc += (float)(int)(u6 & 255u) * h6;
        acc += (float)(int)(u7 & 255u) * h7;
    }
    for (; i + 4 <= end; i += 4) {
        unsigned u0 = ep[i], u1 = ep[i + 1], u2 = ep[i + 2], u3 = ep[i + 3];
        float h0 = (float)H[(size_t)(u0 >> 8) * OUTD + lane];
        float h1 = (float)H[(size_t)(u1 >> 8) * OUTD + lane];
        float h2 = (float)H[(size_t)(u2 >> 8) * OUTD + lane];
        float h3 = (float)H[(size_t)(u3 >> 8) * OUTD + lane];
        acc += (float)(int)(u0 & 255u) * h0;
        acc += (float)(int)(u1 & 255u) * h1;
        acc += (float)(int)(u2 & 255u) * h2;
        acc += (float)(int)(u3 & 255u) * h3;
    }
    for (; i < end; i++) {
        unsigned u = ep[i];
        acc += (float)(int)(u & 255u) * (float)H[(size_t)(u >> 8) * OUTD + lane];
    }
    acc *= (1.f / 255.f);
    if (LAST) Zf[(size_t)wave * OUTD + lane] = acc;
    else      Zh[(size_t)wave * OUTD + lane] = (_Float16)acc;
}

extern "C" void kernel_launch(void* const* d_in, const int* in_sizes, int n_in,
                              void* d_out, int out_size, void* d_ws, size_t ws_size,
                              hipStream_t stream) {
    const float* F   = (const float*)d_in[0];
    const float* W1  = (const float*)d_in[1];
    const float* W2  = (const float*)d_in[2];
    const float* ew  = (const float*)d_in[3];
    const int*   src = (const int*)d_in[4];
    const int*   dst = (const int*)d_in[5];
    float* out = (float*)d_out;
    const int nE = in_sizes[3];

    // ---- workspace layout ----
    char* p = (char*)d_ws;
    _Float16*  h2        = (_Float16*)p;  p += (size_t)NN * OUTD * sizeof(_Float16);   // 12.8 MB
    _Float16*  z1        = (_Float16*)p;  p += (size_t)NN * OUTD * sizeof(_Float16);   // 12.8 MB
    _Float16*  W1t       = (_Float16*)p;  p += (size_t)HID * IND * sizeof(_Float16);
    _Float16*  W2t       = (_Float16*)p;  p += (size_t)OUTD * HID * sizeof(_Float16);
    int*       counts    = (int*)p;       p += (size_t)NBUCK * NB * sizeof(int);       // 800 KB
    int*       bsum      = (int*)p;       p += (size_t)NBUCK * sizeof(int);
    int*       bucketStart=(int*)p;       p += (size_t)(NBUCK + 16) * sizeof(int);
    int*       rowStart  = (int*)p;       p += (size_t)(NN + 160) * sizeof(int);       // 400 KB
    unsigned*  edata     = (unsigned*)p;  p += (size_t)nE * sizeof(unsigned);          // 12.8 MB
    unsigned*  epack     = (unsigned*)p;  p += (size_t)nE * sizeof(unsigned);          // 12.8 MB

    const int CH = (nE + NB - 1) / NB;   // 12500

    // ---- partition chain (count||prep fused; no global atomics anywhere) ----
    countprep_k<<<NB + NPREP, 1024, 0, stream>>>(dst, counts, nE, CH, W1, W2, W1t, W2t);
    bsum_k<<<NBUCK, 256, 0, stream>>>(counts, bsum);
    scan_top_k<<<1, 1024, 0, stream>>>(bsum, bucketStart, NBUCK);
    boff_k<<<NBUCK, 256, 0, stream>>>(counts, bucketStart);
    part_k<<<NB, 1024, 0, stream>>>(src, dst, ew, counts, edata, nE, CH);

    // ---- sort || fused gemm in one launch ----
    gemmsort_k<<<NBUCK + NGEMM, 256, 0, stream>>>(F, W1t, W2t, h2,
                                                  edata, bucketStart, epack, rowStart);

    // ---- 2x pull-propagate (f16 gathers, f32 accum) ----
    int blocks = (int)(((long)NN * 64 + 255) / 256);
    pull_k<false><<<blocks, 256, 0, stream>>>(h2, epack, rowStart, z1, nullptr);
    pull_k<true><<<blocks, 256, 0, stream>>>(z1, epack, rowStart, nullptr, out);
}